// Round 2
// baseline (796.004 us; speedup 1.0000x reference)
//
#include <hip/hip_runtime.h>

typedef __bf16 bf16_t;
typedef __bf16 bf16x4 __attribute__((ext_vector_type(4)));
typedef __bf16 bf16x8 __attribute__((ext_vector_type(8)));
typedef float f32x4 __attribute__((ext_vector_type(4)));

#define GLL16(gp, lp) __builtin_amdgcn_global_load_lds( \
    (__attribute__((address_space(1))) void*)(gp),      \
    (__attribute__((address_space(3))) void*)(lp), 16, 0, 0)

// ---------------------------------------------------------------------------
// 256x256-tile 8-phase GEMM (guide §5 template, plain HIP).
//   C[half][M,N] = epi(A[half][M,K] @ W[half][N,K]^T + bias[half])
// 512 threads = 8 waves (2M x 4N); per-wave output 128x64.
// BK=64; LDS 128 KiB (2 dbuf x (A 256x64 + B 256x64) bf16).
// Swizzle: 16B-granule XOR by row&7, applied on global source (staging) and
// on ds_read (both-sides involution, rule 21) -> conflict-free ds_read_b128.
// 4 phases per K-tile: phase p computes m-pair {2p,2p+1} x 4n x 2kk = 16 MFMA.
// Stages for tile t+1 issued in phases 0 (A) and 1 (B); single vmcnt(0) at
// end of phase 3 (~2.5 phases after last issue -> near-free).
// EPI: 0 relu->bf16, 1 bias->bf16, 2 sigmoid(U)*v->bf16, 3 bias->f32
// ---------------------------------------------------------------------------
#define STAGE_A(NXT) do {                                                    \
    _Pragma("unroll") for (int r = 0; r < 4; ++r) {                          \
        GLL16(asrc[r], &As[NXT][(r * 512 + w * 64) * 8]);                    \
        asrc[r] += 64;                                                       \
    } } while (0)

#define STAGE_B(NXT) do {                                                    \
    _Pragma("unroll") for (int r = 0; r < 4; ++r) {                          \
        GLL16(bsrc[r], &Bs[NXT][(r * 512 + w * 64) * 8]);                    \
        bsrc[r] += 64;                                                       \
    } } while (0)

#define LOADA(CUR, m0) do {                                                  \
    _Pragma("unroll") for (int mm = 0; mm < 2; ++mm)                         \
    _Pragma("unroll") for (int kk = 0; kk < 2; ++kk)                         \
        af[mm][kk] = *(const bf16x8*)(aT##CUR + ((m0) + mm) * 1024 +         \
                                      (g0 ^ (kk << 2)) * 8);                 \
    } while (0)

#define PHASE_MFMA(m0)                                                       \
    __builtin_amdgcn_s_barrier();                                            \
    asm volatile("s_waitcnt lgkmcnt(0)" ::: "memory");                       \
    __builtin_amdgcn_sched_barrier(0);                                       \
    __builtin_amdgcn_s_setprio(1);                                           \
    _Pragma("unroll") for (int mm = 0; mm < 2; ++mm)                         \
    _Pragma("unroll") for (int n = 0; n < 4; ++n)                            \
    _Pragma("unroll") for (int kk = 0; kk < 2; ++kk)                         \
        acc[(m0) + mm][n] = __builtin_amdgcn_mfma_f32_16x16x32_bf16(         \
            af[mm][kk], bq[n][kk], acc[(m0) + mm][n], 0, 0, 0);              \
    __builtin_amdgcn_s_setprio(0);

#define ITER(CUR, NXT, doStage) do {                                         \
    /* phase 0: 8 b-frag + 4 a-frag ds_reads; stage A of tile t+1 */         \
    _Pragma("unroll") for (int n = 0; n < 4; ++n)                            \
    _Pragma("unroll") for (int kk = 0; kk < 2; ++kk)                         \
        bq[n][kk] = *(const bf16x8*)(bT##CUR + n * 1024 +                    \
                                     (g0 ^ (kk << 2)) * 8);                  \
    LOADA(CUR, 0);                                                           \
    if (doStage) { STAGE_A(NXT); }                                           \
    PHASE_MFMA(0);                                                           \
    __builtin_amdgcn_s_barrier();                                            \
    /* phase 1: stage B of tile t+1 */                                       \
    LOADA(CUR, 2);                                                           \
    if (doStage) { STAGE_B(NXT); }                                           \
    PHASE_MFMA(2);                                                           \
    __builtin_amdgcn_s_barrier();                                            \
    /* phase 2 */                                                            \
    LOADA(CUR, 4);                                                           \
    PHASE_MFMA(4);                                                           \
    __builtin_amdgcn_s_barrier();                                            \
    /* phase 3: drain tile t+1 stages, then flip */                          \
    LOADA(CUR, 6);                                                           \
    PHASE_MFMA(6);                                                           \
    asm volatile("s_waitcnt vmcnt(0)" ::: "memory");                         \
    __builtin_amdgcn_s_barrier();                                            \
    } while (0)

template<int EPI>
__global__ __launch_bounds__(512, 2)
void gemm256(const bf16_t* __restrict__ A0, const bf16_t* __restrict__ A1, int lda,
             const bf16_t* __restrict__ W0, const bf16_t* __restrict__ W1,
             const float* __restrict__ bias0, const float* __restrict__ bias1,
             const bf16_t* __restrict__ U0, const bf16_t* __restrict__ U1,
             void* __restrict__ C0v, void* __restrict__ C1v, int ldc,
             int K, int nbx, int nbyH)
{
    __shared__ bf16_t As[2][16384];
    __shared__ bf16_t Bs[2][16384];

    const int t = threadIdx.x;
    const int w = t >> 6, l = t & 63;
    const int wr = w >> 2, wc = w & 3;        // 2 x 4 wave grid
    const int ro = l & 15, hi = l >> 4;
    const int g0 = hi ^ (ro & 7);             // swizzled granule, kk=0

    // bijective XCD swizzle (nwg % 8 == 0), bx-major linearization:
    // each XCD owns contiguous column-groups -> W slice L2-resident.
    const int nwg = gridDim.x;
    int lin = blockIdx.x;
    lin = (lin & 7) * (nwg >> 3) + (lin >> 3);
    const int c   = lin / nbyH;
    const int byh = lin - c * nbyH;
    const int sel = (c >= nbx) ? 1 : 0;
    const int bx  = c - sel * nbx;

    const bf16_t* A    = sel ? A1 : A0;
    const bf16_t* W    = sel ? W1 : W0;
    const float*  bias = sel ? bias1 : bias0;
    const bf16_t* Up   = sel ? U1 : U0;
    void*         Cp   = sel ? C1v : C0v;

    const bf16_t* Ab = A + (size_t)byh * 256 * lda;
    const bf16_t* Wb = W + (size_t)bx * 256 * K;

    // pre-swizzled per-lane global sources (inverse of the ds_read swizzle)
    const bf16_t* asrc[4];
    const bf16_t* bsrc[4];
#pragma unroll
    for (int r = 0; r < 4; ++r) {
        const int g   = r * 512 + t;          // 16B granule id in 256x64 tile
        const int row = g >> 3;
        const int cg  = (g & 7) ^ (row & 7);
        asrc[r] = Ab + (size_t)row * lda + cg * 8;
        bsrc[r] = Wb + (size_t)row * K   + cg * 8;
    }

    const bf16_t* aT0 = &As[0][(wr * 128 + ro) * 64];
    const bf16_t* aT1 = &As[1][(wr * 128 + ro) * 64];
    const bf16_t* bT0 = &Bs[0][(wc * 64 + ro) * 64];
    const bf16_t* bT1 = &Bs[1][(wc * 64 + ro) * 64];

    f32x4 acc[8][4] = {};
    bf16x8 bq[4][2];
    bf16x8 af[2][2];

    // prologue: stage tile 0 into buf0, full drain once
    STAGE_A(0);
    STAGE_B(0);
    asm volatile("s_waitcnt vmcnt(0)" ::: "memory");
    __builtin_amdgcn_s_barrier();

    const int NT = K >> 6;                    // K-tiles (even)
    for (int tp = 0; tp < NT; tp += 2) {
        ITER(0, 1, true);                     // tp+1 < NT always holds here
        ITER(1, 0, (tp + 2 < NT));
    }

    // epilogue: C/D frag layout col=lane&15, row=(lane>>4)*4+j  [guide m89]
    const int rbase = byh * 256 + wr * 128 + (hi << 2);
    const int cbase = bx * 256 + wc * 64 + ro;
#pragma unroll
    for (int n = 0; n < 4; ++n) {
        const int col = cbase + n * 16;
        const float bcol = bias[col];
#pragma unroll
        for (int m = 0; m < 8; ++m) {
#pragma unroll
            for (int j = 0; j < 4; ++j) {
                const int row = rbase + m * 16 + j;
                float v = acc[m][n][j] + bcol;
                if (EPI == 0) v = fmaxf(v, 0.0f);
                if (EPI == 2) {
                    const float u = (float)Up[(size_t)row * ldc + col];
                    v *= 1.0f / (1.0f + __expf(-u));
                }
                if (EPI == 3) ((float*)Cp)[(size_t)row * ldc + col] = v;
                else          ((bf16_t*)Cp)[(size_t)row * ldc + col] = (bf16_t)v;
            }
        }
    }
}

// ---------------------------------------------------------------------------
struct WSrcs { const float* p[10]; };

__global__ __launch_bounds__(256)
void cast_weights(WSrcs srcs, bf16_t* __restrict__ dst)
{
    const int region = blockIdx.x >> 10;
    const float* src = srcs.p[region];
    const size_t base = (size_t)(blockIdx.x & 1023) * 1024 + threadIdx.x * 4;
    const float4 f = *(const float4*)(src + base);
    bf16x4 h = {(bf16_t)f.x, (bf16_t)f.y, (bf16_t)f.z, (bf16_t)f.w};
    *(bf16x4*)(dst + ((size_t)region << 20) + base) = h;
}

__global__ __launch_bounds__(256)
void cast_act(const float* __restrict__ src, bf16_t* __restrict__ dst)
{
    const size_t i = ((size_t)blockIdx.x * 256 + threadIdx.x) * 4;
    const float4 f = *(const float4*)(src + i);
    bf16x4 h = {(bf16_t)f.x, (bf16_t)f.y, (bf16_t)f.z, (bf16_t)f.w};
    *(bf16x4*)(dst + i) = h;
}

__global__ __launch_bounds__(256)
void concat_bias(const float* __restrict__ a, const float* __restrict__ b,
                 float* __restrict__ dst)
{
    const int i = blockIdx.x * 256 + threadIdx.x;
    if (i < 1024) dst[i] = a[i];
    else if (i < 2048) dst[i] = b[i - 1024];
}

// ---------------------------------------------------------------------------
// One block per row: dual l2norm + sigmoid gate + exact top-80 (radix select
// on abs bits, stable lowest-index tie-break) + sparse write + visual concat.
// ---------------------------------------------------------------------------
__global__ __launch_bounds__(256)
void finalize_topk(float* __restrict__ AgF,      // OUT2: in Ag, out final
                   float* __restrict__ AlF,      // OUT3: in Al, out f2
                   const float* __restrict__ VIS,
                   float* __restrict__ O1)
{
    const int row = blockIdx.x, t = threadIdx.x;
    __shared__ int bins[256];
    __shared__ int sscan[256];
    __shared__ float wred[8];
    __shared__ int s_sel, s_kk;

    float* agp = AgF + (size_t)row * 1024 + t * 4;
    float* alp = AlF + (size_t)row * 1024 + t * 4;
    const float4 a4 = *(const float4*)agp;
    const float4 l4 = *(const float4*)alp;
    float av[4] = {a4.x, a4.y, a4.z, a4.w};
    float lv[4] = {l4.x, l4.y, l4.z, l4.w};
    float sa = 0.0f, sb = 0.0f;
#pragma unroll
    for (int j = 0; j < 4; ++j) { sa += av[j] * av[j]; sb += lv[j] * lv[j]; }
#pragma unroll
    for (int o = 32; o > 0; o >>= 1) {
        sa += __shfl_down(sa, o);
        sb += __shfl_down(sb, o);
    }
    if ((t & 63) == 0) { wred[t >> 6] = sa; wred[4 + (t >> 6)] = sb; }
    __syncthreads();
    const float sca = 1.0f / fmaxf(sqrtf(wred[0] + wred[1] + wred[2] + wred[3]), 1e-12f);
    const float scl = 1.0f / fmaxf(sqrtf(wred[4] + wred[5] + wred[6] + wred[7]), 1e-12f);

    float fv[4], f2v[4];
    unsigned ab[4];
#pragma unroll
    for (int j = 0; j < 4; ++j) {
        const float f2 = lv[j] * scl;
        const float f1 = av[j] * sca;
        const float fin = f2 / (1.0f + __expf(-f1));   // sigmoid(f1)*f2
        f2v[j] = f2; fv[j] = fin;
        ab[j] = __float_as_uint(fin) & 0x7fffffffu;
    }
    *(float4*)alp = make_float4(f2v[0], f2v[1], f2v[2], f2v[3]);
    *(float4*)agp = make_float4(fv[0], fv[1], fv[2], fv[3]);

    const float* vr = VIS + (size_t)row * 2048;
    float* o1r = O1 + (size_t)row * 3072;
    *(float4*)(o1r + t * 4)        = *(const float4*)(vr + t * 4);
    *(float4*)(o1r + 1024 + t * 4) = *(const float4*)(vr + 1024 + t * 4);

    // --- radix select: exact bits of the 80th-largest |fin| ---
    unsigned pref = 0u, msk = 0u;
    int kk = 80;
    for (int bp = 3; bp >= 0; --bp) {
        bins[t] = 0;
        __syncthreads();
#pragma unroll
        for (int j = 0; j < 4; ++j)
            if ((ab[j] & msk) == pref)
                atomicAdd(&bins[(ab[j] >> (bp * 8)) & 255], 1);
        __syncthreads();
        sscan[t] = bins[t];
        __syncthreads();
        for (int o = 1; o < 256; o <<= 1) {           // suffix sum
            const int add = (t + o < 256) ? sscan[t + o] : 0;
            __syncthreads();
            sscan[t] += add;
            __syncthreads();
        }
        const int Sme = sscan[t];
        const int Snx = (t < 255) ? sscan[t + 1] : 0;
        if (Sme >= kk && Snx < kk) { s_sel = t; s_kk = kk - Snx; }
        __syncthreads();
        pref |= (unsigned)s_sel << (bp * 8);
        msk  |= 0xFFu << (bp * 8);
        kk = s_kk;
        __syncthreads();
    }

    // stable tie-break: keep first kk elements equal to threshold (index order)
    int ec = 0;
#pragma unroll
    for (int j = 0; j < 4; ++j) ec += (ab[j] == pref) ? 1 : 0;
    sscan[t] = ec;
    __syncthreads();
    for (int o = 1; o < 256; o <<= 1) {               // inclusive prefix sum
        const int add = (t >= o) ? sscan[t - o] : 0;
        __syncthreads();
        sscan[t] += add;
        __syncthreads();
    }
    int excl = sscan[t] - ec;
#pragma unroll
    for (int j = 0; j < 4; ++j) {
        const bool eq = (ab[j] == pref);
        const bool kp = (ab[j] > pref) || (eq && (excl < kk));
        o1r[2048 + t * 4 + j] = kp ? fv[j] : 0.0f;
        if (eq) ++excl;
    }
}

// ---------------------------------------------------------------------------
extern "C" void kernel_launch(void* const* d_in, const int* in_sizes, int n_in,
                              void* d_out, int out_size, void* d_ws, size_t ws_size,
                              hipStream_t stream)
{
    const float* SG   = (const float*)d_in[0];
    const float* SL   = (const float*)d_in[1];
    const float* VIS  = (const float*)d_in[2];
    const float* Wgu1 = (const float*)d_in[3];  // bgu1 = d_in[4] (zeros, still used)
    const float* bgu1 = (const float*)d_in[4];
    const float* Wgu2 = (const float*)d_in[5];  const float* bgu2 = (const float*)d_in[6];
    const float* Wgd1 = (const float*)d_in[7];  const float* bgd1 = (const float*)d_in[8];
    const float* Wgd2 = (const float*)d_in[9];  const float* bgd2 = (const float*)d_in[10];
    const float* Wlu1 = (const float*)d_in[11]; const float* blu1 = (const float*)d_in[12];
    const float* Wlu2 = (const float*)d_in[13]; const float* blu2 = (const float*)d_in[14];
    const float* Wld1 = (const float*)d_in[15]; const float* bld1 = (const float*)d_in[16];
    const float* Wld2 = (const float*)d_in[17]; const float* bld2 = (const float*)d_in[18];
    const float* Wo   = (const float*)d_in[19]; const float* bo   = (const float*)d_in[20];
    const float* Win  = (const float*)d_in[21]; const float* bin_ = (const float*)d_in[22];
    const float* Wv = Win + (size_t)2 * 1024 * 1024;   // Win[2E:]
    const float* bv = bin_ + 2048;

    float* OUT1 = (float*)d_out;                         // B x 3072
    float* OUT2 = OUT1 + (size_t)16384 * 3072;           // B x 1024 (final)
    float* OUT3 = OUT2 + (size_t)16384 * 1024;           // B x 1024 (f2)

    // ws: bf16 weights + concat'd biases
    char* ws = (char*)d_ws;
    bf16_t* Wbf = (bf16_t*)ws;                           // 10M bf16
    float*  bb  = (float*)(ws + 20971520);               // 4096 f32

    // scratch inside d_out (320 MiB total), lifetime-checked:
    //   X   [  0, 32) MiB   cast sg        (dead after D4; D3 rewrites as sg')
    //   Y   [ 32, 64) MiB   cast sl        (ditto)
    //   Ug  [ 64, 96) MiB   gate pre-act g (dead after D3)
    //   Ul  [ 96,128) MiB   gate pre-act l (dead after D3)
    //   V   [ 64,128) MiB   D4 out (overwrites Ug/Ul; read by D5)
    //   H1g [128,192) MiB   hidden g       (dead after D3)
    //   H1l [192,256) MiB   hidden l       (dead after D3; D5 writes OUT2 here)
    //   OUT2/OUT3 [192,320) MiB written by D5; finalize overwrites X..H1g w/ OUT1
    bf16_t* X   = (bf16_t*)d_out;
    bf16_t* Y   = X + (size_t)16384 * 1024;
    bf16_t* Ug  = (bf16_t*)((char*)d_out + 67108864);
    bf16_t* Ul  = (bf16_t*)((char*)d_out + 100663296);
    bf16_t* V   = (bf16_t*)((char*)d_out + 67108864);
    bf16_t* V2  = V + (size_t)16384 * 1024;
    bf16_t* H1g = (bf16_t*)((char*)d_out + 134217728);
    bf16_t* H1l = (bf16_t*)((char*)d_out + 201326592);

    WSrcs srcs;
    srcs.p[0] = Wgu1; srcs.p[1] = Wgd1; srcs.p[2] = Wlu1; srcs.p[3] = Wld1;
    srcs.p[4] = Wgu2; srcs.p[5] = Wgd2; srcs.p[6] = Wlu2; srcs.p[7] = Wld2;
    srcs.p[8] = Wv;   srcs.p[9] = Wo;

    cast_weights<<<10240, 256, 0, stream>>>(srcs, Wbf);
    concat_bias<<<8, 256, 0, stream>>>(bgu1, bgd1, bb);
    concat_bias<<<8, 256, 0, stream>>>(blu1, bld1, bb + 2048);
    cast_act<<<16384, 256, 0, stream>>>(SG, X);
    cast_act<<<16384, 256, 0, stream>>>(SL, Y);

    bf16_t* Wg1   = Wbf;                                 // [Wgu1;Wgd1] 2048x1024
    bf16_t* Wl1   = Wbf + (size_t)2 * 1048576;           // [Wlu1;Wld1]
    bf16_t* Wgu2b = Wbf + (size_t)4 * 1048576;
    bf16_t* Wgd2b = Wbf + (size_t)5 * 1048576;
    bf16_t* Wlu2b = Wbf + (size_t)6 * 1048576;
    bf16_t* Wld2b = Wbf + (size_t)7 * 1048576;
    bf16_t* Wvb   = Wbf + (size_t)8 * 1048576;
    bf16_t* Wob   = Wbf + (size_t)9 * 1048576;

    // D1: h1 = relu([X;Y] @ [W?u1;W?d1]^T + b), per-half weights. N=2048.
    gemm256<0><<<1024, 512, 0, stream>>>(X, Y, 1024, Wg1, Wl1, bb, bb + 2048,
                                         nullptr, nullptr, H1g, H1l, 2048, 1024, 8, 64);
    // D2: U = h1[:, :1024] @ W?u2^T + b  (gate pre-act)
    gemm256<1><<<512, 512, 0, stream>>>(H1g, H1l, 2048, Wgu2b, Wlu2b, bgu2, blu2,
                                        nullptr, nullptr, Ug, Ul, 1024, 1024, 4, 64);
    // D3: s? = sigmoid(U) * (h1[:, 1024:] @ W?d2^T + b)  -> X, Y
    gemm256<2><<<512, 512, 0, stream>>>(H1g + 1024, H1l + 1024, 2048, Wgd2b, Wld2b,
                                        bgd2, bld2, Ug, Ul, X, Y, 1024, 1024, 4, 64);
    // D4: V = [sg;sl] @ Wv^T + bv
    gemm256<1><<<512, 512, 0, stream>>>(X, Y, 1024, Wvb, Wvb, bv, bv,
                                        nullptr, nullptr, V, V2, 1024, 1024, 4, 64);
    // D5: pre-norm attn_out = V @ Wo^T + bo  -> OUT2 (sg rows), OUT3 (sl rows)
    gemm256<3><<<512, 512, 0, stream>>>(V, V2, 1024, Wob, Wob, bo, bo,
                                        nullptr, nullptr, OUT2, OUT3, 1024, 1024, 4, 64);

    finalize_topk<<<16384, 256, 0, stream>>>(OUT2, OUT3, VIS, OUT1);
}

// Round 3
// 735.244 us; speedup vs baseline: 1.0826x; 1.0826x over previous
//
#include <hip/hip_runtime.h>

typedef __bf16 bf16_t;
typedef __bf16 bf16x4 __attribute__((ext_vector_type(4)));
typedef __bf16 bf16x8 __attribute__((ext_vector_type(8)));
typedef float f32x4 __attribute__((ext_vector_type(4)));

#define GLL16(gp, lp) __builtin_amdgcn_global_load_lds( \
    (__attribute__((address_space(1))) void*)(gp),      \
    (__attribute__((address_space(3))) void*)(lp), 16, 0, 0)

// ---------------------------------------------------------------------------
// 256x256-tile 4-phase/K-tile GEMM.
//   C[half][M,N] = epi(A[half][M,K] @ W[half][N,K]^T + bias[half])
// 512 threads = 8 waves (2M x 4N); per-wave output 128x64.
// BK=64; LDS 128 KiB (2 dbuf x (A 256x64 + B 256x64) bf16).
// Swizzle: 16B-granule XOR by row&7 on both global source and ds_read.
// Staging: all 8 global_load_lds for tile t+1 issued at phase 0 of tile t
// (dbuf -> target buffer is idle the whole tile); single vmcnt(0) at end of
// phase 3 waits on loads ~3.5 phases (~1000 cy) old.
// Epilogue: n-innermost store order -> each 128B C-line written by 4
// consecutive 32B wave-stores (full-line write combining, no RMW).
// Block remap: XCD owns 8 byh rows x all c; 8x4 (byh x c) windows keep
// A (4 MiB) + W (2 MiB) concurrently live per-XCD-L2.
// EPI: 0 relu->bf16, 1 bias->bf16, 2 sigmoid(U)*v->bf16, 3 bias->f32
// ---------------------------------------------------------------------------
#define STAGE_ALL(NXT) do {                                                  \
    _Pragma("unroll") for (int r = 0; r < 4; ++r) {                          \
        GLL16(asrc[r], &As[NXT][(r * 512 + w * 64) * 8]);                    \
        asrc[r] += 64;                                                       \
    }                                                                        \
    _Pragma("unroll") for (int r = 0; r < 4; ++r) {                          \
        GLL16(bsrc[r], &Bs[NXT][(r * 512 + w * 64) * 8]);                    \
        bsrc[r] += 64;                                                       \
    } } while (0)

#define LOADA(CUR, m0) do {                                                  \
    _Pragma("unroll") for (int mm = 0; mm < 2; ++mm)                         \
    _Pragma("unroll") for (int kk = 0; kk < 2; ++kk)                         \
        af[mm][kk] = *(const bf16x8*)(aT##CUR + ((m0) + mm) * 1024 +         \
                                      (g0 ^ (kk << 2)) * 8);                 \
    } while (0)

#define PHASE_MFMA(m0)                                                       \
    __builtin_amdgcn_s_barrier();                                            \
    asm volatile("s_waitcnt lgkmcnt(0)" ::: "memory");                       \
    __builtin_amdgcn_sched_barrier(0);                                       \
    __builtin_amdgcn_s_setprio(1);                                           \
    _Pragma("unroll") for (int mm = 0; mm < 2; ++mm)                         \
    _Pragma("unroll") for (int n = 0; n < 4; ++n)                            \
    _Pragma("unroll") for (int kk = 0; kk < 2; ++kk)                         \
        acc[(m0) + mm][n] = __builtin_amdgcn_mfma_f32_16x16x32_bf16(         \
            af[mm][kk], bq[n][kk], acc[(m0) + mm][n], 0, 0, 0);              \
    __builtin_amdgcn_s_setprio(0);

#define ITER(CUR, NXT, doStage) do {                                         \
    /* phase 0: stage ALL of tile t+1; read all B-frags + A m0,m1 */         \
    if (doStage) { STAGE_ALL(NXT); }                                         \
    _Pragma("unroll") for (int n = 0; n < 4; ++n)                            \
    _Pragma("unroll") for (int kk = 0; kk < 2; ++kk)                         \
        bq[n][kk] = *(const bf16x8*)(bT##CUR + n * 1024 +                    \
                                     (g0 ^ (kk << 2)) * 8);                  \
    LOADA(CUR, 0);                                                           \
    PHASE_MFMA(0);                                                           \
    __builtin_amdgcn_s_barrier();                                            \
    LOADA(CUR, 2);                                                           \
    PHASE_MFMA(2);                                                           \
    __builtin_amdgcn_s_barrier();                                            \
    LOADA(CUR, 4);                                                           \
    PHASE_MFMA(4);                                                           \
    __builtin_amdgcn_s_barrier();                                            \
    LOADA(CUR, 6);                                                           \
    PHASE_MFMA(6);                                                           \
    asm volatile("s_waitcnt vmcnt(0)" ::: "memory");                         \
    __builtin_amdgcn_s_barrier();                                            \
    } while (0)

template<int EPI>
__global__ __launch_bounds__(512, 2)
void gemm256(const bf16_t* __restrict__ A0, const bf16_t* __restrict__ A1, int lda,
             const bf16_t* __restrict__ W0, const bf16_t* __restrict__ W1,
             const float* __restrict__ bias0, const float* __restrict__ bias1,
             const bf16_t* __restrict__ U0, const bf16_t* __restrict__ U1,
             void* __restrict__ C0v, void* __restrict__ C1v, int ldc,
             int K, int nbx, int nbyH)
{
    __shared__ bf16_t As[2][16384];
    __shared__ bf16_t Bs[2][16384];

    const int t = threadIdx.x;
    const int w = t >> 6, l = t & 63;
    const int wr = w >> 2, wc = w & 3;        // 2 x 4 wave grid
    const int ro = l & 15, hi = l >> 4;
    const int g0 = hi ^ (ro & 7);             // swizzled granule, kk=0

    // XCD-window remap (requires gridDim%8==0, nbyH%8==0, c_total%4==0):
    // XCD owns nbyH/8 consecutive byh rows x all c; within, 8x4 (byh x c)
    // windows so the ~32 concurrent blocks/XCD share A panels in L2.
    const int xcd   = blockIdx.x & 7;
    const int local = blockIdx.x >> 3;
    const int cg    = local >> 5;
    const int r5    = local & 31;
    const int byh   = xcd * (nbyH >> 3) + (r5 >> 2);
    const int c     = cg * 4 + (r5 & 3);
    const int sel   = (c >= nbx) ? 1 : 0;
    const int bx    = c - sel * nbx;

    const bf16_t* A    = sel ? A1 : A0;
    const bf16_t* W    = sel ? W1 : W0;
    const float*  bias = sel ? bias1 : bias0;
    const bf16_t* Up   = sel ? U1 : U0;
    void*         Cp   = sel ? C1v : C0v;

    const bf16_t* Ab = A + (size_t)byh * 256 * lda;
    const bf16_t* Wb = W + (size_t)bx * 256 * K;

    // pre-swizzled per-lane global sources (inverse of the ds_read swizzle)
    const bf16_t* asrc[4];
    const bf16_t* bsrc[4];
#pragma unroll
    for (int r = 0; r < 4; ++r) {
        const int g   = r * 512 + t;          // 16B granule id in 256x64 tile
        const int row = g >> 3;
        const int cgr = (g & 7) ^ (row & 7);
        asrc[r] = Ab + (size_t)row * lda + cgr * 8;
        bsrc[r] = Wb + (size_t)row * K   + cgr * 8;
    }

    const bf16_t* aT0 = &As[0][(wr * 128 + ro) * 64];
    const bf16_t* aT1 = &As[1][(wr * 128 + ro) * 64];
    const bf16_t* bT0 = &Bs[0][(wc * 64 + ro) * 64];
    const bf16_t* bT1 = &Bs[1][(wc * 64 + ro) * 64];

    f32x4 acc[8][4] = {};
    bf16x8 bq[4][2];
    bf16x8 af[2][2];

    // prologue: stage tile 0 into buf0, full drain once
    STAGE_ALL(0);
    asm volatile("s_waitcnt vmcnt(0)" ::: "memory");
    __builtin_amdgcn_s_barrier();

    const int NT = K >> 6;                    // K-tiles (even)
    for (int tp = 0; tp < NT; tp += 2) {
        ITER(0, 1, true);                     // tp+1 < NT always holds here
        ITER(1, 0, (tp + 2 < NT));
    }

    // epilogue: C/D frag layout col=lane&15, row=(lane>>4)*4+j  [guide m89]
    // n-innermost: each 128B line gets its 4x32B stores back-to-back.
    const int rbase = byh * 256 + wr * 128 + (hi << 2);
    const int cbase = bx * 256 + wc * 64 + ro;
    float bc[4];
#pragma unroll
    for (int n = 0; n < 4; ++n) bc[n] = bias[cbase + n * 16];
#pragma unroll
    for (int m = 0; m < 8; ++m) {
#pragma unroll
        for (int j = 0; j < 4; ++j) {
            const int row = rbase + m * 16 + j;
            const size_t off = (size_t)row * ldc + cbase;
#pragma unroll
            for (int n = 0; n < 4; ++n) {
                float v = acc[m][n][j] + bc[n];
                if (EPI == 0) v = fmaxf(v, 0.0f);
                if (EPI == 2) {
                    const float u = (float)Up[off + n * 16];
                    v *= 1.0f / (1.0f + __expf(-u));
                }
                if (EPI == 3) ((float*)Cp)[off + n * 16] = v;
                else          ((bf16_t*)Cp)[off + n * 16] = (bf16_t)v;
            }
        }
    }
}

// ---------------------------------------------------------------------------
struct WSrcs { const float* p[10]; };

__global__ __launch_bounds__(256)
void cast_weights(WSrcs srcs, bf16_t* __restrict__ dst)
{
    const int region = blockIdx.x >> 10;
    const float* src = srcs.p[region];
    const size_t base = (size_t)(blockIdx.x & 1023) * 1024 + threadIdx.x * 4;
    const float4 f = *(const float4*)(src + base);
    bf16x4 h = {(bf16_t)f.x, (bf16_t)f.y, (bf16_t)f.z, (bf16_t)f.w};
    *(bf16x4*)(dst + ((size_t)region << 20) + base) = h;
}

__global__ __launch_bounds__(256)
void cast_act(const float* __restrict__ src, bf16_t* __restrict__ dst)
{
    const size_t i = ((size_t)blockIdx.x * 256 + threadIdx.x) * 4;
    const float4 f = *(const float4*)(src + i);
    bf16x4 h = {(bf16_t)f.x, (bf16_t)f.y, (bf16_t)f.z, (bf16_t)f.w};
    *(bf16x4*)(dst + i) = h;
}

__global__ __launch_bounds__(256)
void concat_bias(const float* __restrict__ a, const float* __restrict__ b,
                 float* __restrict__ dst)
{
    const int i = blockIdx.x * 256 + threadIdx.x;
    if (i < 1024) dst[i] = a[i];
    else if (i < 2048) dst[i] = b[i - 1024];
}

// ---------------------------------------------------------------------------
// One block per row: dual l2norm + sigmoid gate + exact top-80 (radix select
// on abs bits, stable lowest-index tie-break) + sparse write + visual concat.
// ---------------------------------------------------------------------------
__global__ __launch_bounds__(256)
void finalize_topk(float* __restrict__ AgF,      // OUT2: in Ag, out final
                   float* __restrict__ AlF,      // OUT3: in Al, out f2
                   const float* __restrict__ VIS,
                   float* __restrict__ O1)
{
    const int row = blockIdx.x, t = threadIdx.x;
    __shared__ int bins[256];
    __shared__ int sscan[256];
    __shared__ float wred[8];
    __shared__ int s_sel, s_kk;

    float* agp = AgF + (size_t)row * 1024 + t * 4;
    float* alp = AlF + (size_t)row * 1024 + t * 4;
    const float4 a4 = *(const float4*)agp;
    const float4 l4 = *(const float4*)alp;
    float av[4] = {a4.x, a4.y, a4.z, a4.w};
    float lv[4] = {l4.x, l4.y, l4.z, l4.w};
    float sa = 0.0f, sb = 0.0f;
#pragma unroll
    for (int j = 0; j < 4; ++j) { sa += av[j] * av[j]; sb += lv[j] * lv[j]; }
#pragma unroll
    for (int o = 32; o > 0; o >>= 1) {
        sa += __shfl_down(sa, o);
        sb += __shfl_down(sb, o);
    }
    if ((t & 63) == 0) { wred[t >> 6] = sa; wred[4 + (t >> 6)] = sb; }
    __syncthreads();
    const float sca = 1.0f / fmaxf(sqrtf(wred[0] + wred[1] + wred[2] + wred[3]), 1e-12f);
    const float scl = 1.0f / fmaxf(sqrtf(wred[4] + wred[5] + wred[6] + wred[7]), 1e-12f);

    float fv[4], f2v[4];
    unsigned ab[4];
#pragma unroll
    for (int j = 0; j < 4; ++j) {
        const float f2 = lv[j] * scl;
        const float f1 = av[j] * sca;
        const float fin = f2 / (1.0f + __expf(-f1));   // sigmoid(f1)*f2
        f2v[j] = f2; fv[j] = fin;
        ab[j] = __float_as_uint(fin) & 0x7fffffffu;
    }
    *(float4*)alp = make_float4(f2v[0], f2v[1], f2v[2], f2v[3]);
    *(float4*)agp = make_float4(fv[0], fv[1], fv[2], fv[3]);

    const float* vr = VIS + (size_t)row * 2048;
    float* o1r = O1 + (size_t)row * 3072;
    *(float4*)(o1r + t * 4)        = *(const float4*)(vr + t * 4);
    *(float4*)(o1r + 1024 + t * 4) = *(const float4*)(vr + 1024 + t * 4);

    // --- radix select: exact bits of the 80th-largest |fin| ---
    unsigned pref = 0u, msk = 0u;
    int kk = 80;
    for (int bp = 3; bp >= 0; --bp) {
        bins[t] = 0;
        __syncthreads();
#pragma unroll
        for (int j = 0; j < 4; ++j)
            if ((ab[j] & msk) == pref)
                atomicAdd(&bins[(ab[j] >> (bp * 8)) & 255], 1);
        __syncthreads();
        sscan[t] = bins[t];
        __syncthreads();
        for (int o = 1; o < 256; o <<= 1) {           // suffix sum
            const int add = (t + o < 256) ? sscan[t + o] : 0;
            __syncthreads();
            sscan[t] += add;
            __syncthreads();
        }
        const int Sme = sscan[t];
        const int Snx = (t < 255) ? sscan[t + 1] : 0;
        if (Sme >= kk && Snx < kk) { s_sel = t; s_kk = kk - Snx; }
        __syncthreads();
        pref |= (unsigned)s_sel << (bp * 8);
        msk  |= 0xFFu << (bp * 8);
        kk = s_kk;
        __syncthreads();
    }

    // stable tie-break: keep first kk elements equal to threshold (index order)
    int ec = 0;
#pragma unroll
    for (int j = 0; j < 4; ++j) ec += (ab[j] == pref) ? 1 : 0;
    sscan[t] = ec;
    __syncthreads();
    for (int o = 1; o < 256; o <<= 1) {               // inclusive prefix sum
        const int add = (t >= o) ? sscan[t - o] : 0;
        __syncthreads();
        sscan[t] += add;
        __syncthreads();
    }
    int excl = sscan[t] - ec;
#pragma unroll
    for (int j = 0; j < 4; ++j) {
        const bool eq = (ab[j] == pref);
        const bool kp = (ab[j] > pref) || (eq && (excl < kk));
        o1r[2048 + t * 4 + j] = kp ? fv[j] : 0.0f;
        if (eq) ++excl;
    }
}

// ---------------------------------------------------------------------------
extern "C" void kernel_launch(void* const* d_in, const int* in_sizes, int n_in,
                              void* d_out, int out_size, void* d_ws, size_t ws_size,
                              hipStream_t stream)
{
    const float* SG   = (const float*)d_in[0];
    const float* SL   = (const float*)d_in[1];
    const float* VIS  = (const float*)d_in[2];
    const float* Wgu1 = (const float*)d_in[3];
    const float* bgu1 = (const float*)d_in[4];
    const float* Wgu2 = (const float*)d_in[5];  const float* bgu2 = (const float*)d_in[6];
    const float* Wgd1 = (const float*)d_in[7];  const float* bgd1 = (const float*)d_in[8];
    const float* Wgd2 = (const float*)d_in[9];  const float* bgd2 = (const float*)d_in[10];
    const float* Wlu1 = (const float*)d_in[11]; const float* blu1 = (const float*)d_in[12];
    const float* Wlu2 = (const float*)d_in[13]; const float* blu2 = (const float*)d_in[14];
    const float* Wld1 = (const float*)d_in[15]; const float* bld1 = (const float*)d_in[16];
    const float* Wld2 = (const float*)d_in[17]; const float* bld2 = (const float*)d_in[18];
    const float* Wo   = (const float*)d_in[19]; const float* bo   = (const float*)d_in[20];
    const float* Win  = (const float*)d_in[21]; const float* bin_ = (const float*)d_in[22];
    const float* Wv = Win + (size_t)2 * 1024 * 1024;   // Win[2E:]
    const float* bv = bin_ + 2048;

    float* OUT1 = (float*)d_out;                         // B x 3072
    float* OUT2 = OUT1 + (size_t)16384 * 3072;           // B x 1024 (final)
    float* OUT3 = OUT2 + (size_t)16384 * 1024;           // B x 1024 (f2)

    // ws: bf16 weights + concat'd biases
    char* ws = (char*)d_ws;
    bf16_t* Wbf = (bf16_t*)ws;                           // 10M bf16
    float*  bb  = (float*)(ws + 20971520);               // 4096 f32

    // scratch inside d_out (320 MiB total), lifetime-checked (see r2 notes)
    bf16_t* X   = (bf16_t*)d_out;
    bf16_t* Y   = X + (size_t)16384 * 1024;
    bf16_t* Ug  = (bf16_t*)((char*)d_out + 67108864);
    bf16_t* Ul  = (bf16_t*)((char*)d_out + 100663296);
    bf16_t* V   = (bf16_t*)((char*)d_out + 67108864);
    bf16_t* V2  = V + (size_t)16384 * 1024;
    bf16_t* H1g = (bf16_t*)((char*)d_out + 134217728);
    bf16_t* H1l = (bf16_t*)((char*)d_out + 201326592);

    WSrcs srcs;
    srcs.p[0] = Wgu1; srcs.p[1] = Wgd1; srcs.p[2] = Wlu1; srcs.p[3] = Wld1;
    srcs.p[4] = Wgu2; srcs.p[5] = Wgd2; srcs.p[6] = Wlu2; srcs.p[7] = Wld2;
    srcs.p[8] = Wv;   srcs.p[9] = Wo;

    cast_weights<<<10240, 256, 0, stream>>>(srcs, Wbf);
    concat_bias<<<8, 256, 0, stream>>>(bgu1, bgd1, bb);
    concat_bias<<<8, 256, 0, stream>>>(blu1, bld1, bb + 2048);
    cast_act<<<16384, 256, 0, stream>>>(SG, X);
    cast_act<<<16384, 256, 0, stream>>>(SL, Y);

    bf16_t* Wg1   = Wbf;                                 // [Wgu1;Wgd1] 2048x1024
    bf16_t* Wl1   = Wbf + (size_t)2 * 1048576;           // [Wlu1;Wld1]
    bf16_t* Wgu2b = Wbf + (size_t)4 * 1048576;
    bf16_t* Wgd2b = Wbf + (size_t)5 * 1048576;
    bf16_t* Wlu2b = Wbf + (size_t)6 * 1048576;
    bf16_t* Wld2b = Wbf + (size_t)7 * 1048576;
    bf16_t* Wvb   = Wbf + (size_t)8 * 1048576;
    bf16_t* Wob   = Wbf + (size_t)9 * 1048576;

    // D1: h1 = relu([X;Y] @ [W?u1;W?d1]^T + b), per-half weights. N=2048.
    gemm256<0><<<1024, 512, 0, stream>>>(X, Y, 1024, Wg1, Wl1, bb, bb + 2048,
                                         nullptr, nullptr, H1g, H1l, 2048, 1024, 8, 64);
    // D2: U = h1[:, :1024] @ W?u2^T + b  (gate pre-act)
    gemm256<1><<<512, 512, 0, stream>>>(H1g, H1l, 2048, Wgu2b, Wlu2b, bgu2, blu2,
                                        nullptr, nullptr, Ug, Ul, 1024, 1024, 4, 64);
    // D3: s? = sigmoid(U) * (h1[:, 1024:] @ W?d2^T + b)  -> X, Y
    gemm256<2><<<512, 512, 0, stream>>>(H1g + 1024, H1l + 1024, 2048, Wgd2b, Wld2b,
                                        bgd2, bld2, Ug, Ul, X, Y, 1024, 1024, 4, 64);
    // D4: V = [sg;sl] @ Wv^T + bv
    gemm256<1><<<512, 512, 0, stream>>>(X, Y, 1024, Wvb, Wvb, bv, bv,
                                        nullptr, nullptr, V, V2, 1024, 1024, 4, 64);
    // D5: pre-norm attn_out = V @ Wo^T + bo  -> OUT2 (sg rows), OUT3 (sl rows)
    gemm256<3><<<512, 512, 0, stream>>>(V, V2, 1024, Wob, Wob, bo, bo,
                                        nullptr, nullptr, OUT2, OUT3, 1024, 1024, 4, 64);

    finalize_topk<<<16384, 256, 0, stream>>>(OUT2, OUT3, VIS, OUT1);
}